// Round 1
// baseline (916.513 us; speedup 1.0000x reference)
//
#include <hip/hip_runtime.h>
#include <stdint.h>

typedef float f4 __attribute__((ext_vector_type(4)));

// phase-rotated (x,y,z) repeating pattern: t=0 -> {x,y,z,x}, t=1 -> {y,z,x,y},
// t=2 -> {z,x,y,z}.
__device__ __forceinline__ f4 rot3(float x, float y, float z, int t) {
    float a0 = (t == 0) ? x : ((t == 1) ? y : z);
    float a1 = (t == 0) ? y : ((t == 1) ? z : x);
    float a2 = (t == 0) ? z : ((t == 1) ? x : y);
    f4 r = {a0, a1, a2, a0};
    return r;
}

// shift_vec = shift_frac @ cell, numpy accumulation order, no fma (bit-exact
// with the reference; image 0 is the zero shift).
__device__ __forceinline__ void shift_vec_for(
    int s, const int* __restrict__ shifts, const float* __restrict__ cell,
    float& svx, float& svy, float& svz)
{
    int sx = 0, sy = 0, sz = 0;
    if (s > 0) {
        sx = shifts[3 * (s - 1) + 0];
        sy = shifts[3 * (s - 1) + 1];
        sz = shifts[3 * (s - 1) + 2];
    }
    float fx = (float)sx, fy = (float)sy, fz = (float)sz;
    svx = __fadd_rn(__fadd_rn(__fmul_rn(fx, cell[0]), __fmul_rn(fy, cell[3])), __fmul_rn(fz, cell[6]));
    svy = __fadd_rn(__fadd_rn(__fmul_rn(fx, cell[1]), __fmul_rn(fy, cell[4])), __fmul_rn(fz, cell[7]));
    svz = __fadd_rn(__fadd_rn(__fmul_rn(fx, cell[2]), __fmul_rn(fy, cell[5])), __fmul_rn(fz, cell[8]));
}

// ---------------------------------------------------------------------------
// Sectioned kernel: one write stream per block, fill-like linear stores.
//
// Output layout (floats): [idx_i 2P][idx_j 2P][offsets 6P][d2 2P][masks 4P]
// viewed as 16 sections of P floats each:
//   0: idx_i lo (pi)   1: idx_i hi (pj)   2: idx_j lo (pj)   3: idx_j hi (pi)
//   4..9: offsets (6P stream: 3P of -shift rows, then 3P of +shift rows)
//   10,11: d2          12,13: mask c0     14,15: mask c1
//
// grid = (P/4096, 16); each block writes ONE contiguous 16 KB chunk of ONE
// section. Requires n_mm % 4096 == 0 (=> P0, P, 3*P0, 3P all 4096-aligned,
// so sec / sign-half / image / ML-row are all block-uniform). Values needed
// by several sections are recomputed per section — VALU is ~5% busy, the
// kernel is purely write-BW bound.
// ---------------------------------------------------------------------------
__global__ __launch_bounds__(256) void nl_sections(
    const float* __restrict__ pos,      // (n_ml+n_mm, 3)
    const float* __restrict__ cell,     // (3,3) row-major
    const float* __restrict__ cutoffs,  // (2,)
    const int*   __restrict__ shifts,   // (S,3)
    const int*   __restrict__ ml_idx,   // (n_ml,)
    const int*   __restrict__ mm_idx,   // (n_mm,)
    float* __restrict__ out,            // float32, 16P elements
    int n_mm, int P0, int P)
{
    const int sec  = blockIdx.y;              // 0..15
    const int tid  = threadIdx.x;
    const int base = blockIdx.x << 12;        // first float of block's chunk
    float* __restrict__ dst =
        out + (size_t)sec * (size_t)P + (size_t)base + ((size_t)tid << 2);

    if (sec >= 4 && sec <= 9) {
        // ---- offsets: pure pattern write, (col = float_pos % 3) ----
        const int o0     = (sec - 4) * P + base;      // [0, 6P)
        const int threeP = 3 * P;
        const bool neg   = (o0 < threeP);             // block-uniform
        const int  oo    = neg ? o0 : (o0 - threeP);  // [0, 3P)
        const int  s     = oo / (3 * P0);             // image (block-uniform)
        float svx, svy, svz;
        shift_vec_for(s, shifts, cell, svx, svy, svz);
        if (neg) { svx = -svx; svy = -svy; svz = -svz; }   // exact
        const int t0 = (oo + (tid << 2)) % 3;
#pragma unroll
        for (int w = 0; w < 4; ++w) {
            int t = t0 + w;                    // 1024 % 3 == 1
            if (t >= 3) t -= 3;
            if (t >= 3) t -= 3;
            *(f4*)(dst + (w << 10)) = rot3(svx, svy, svz, t);
        }
        return;
    }

    // ---- pair-indexed sections: pair p = base + w*1024 + tid*4 + k ----
    const int s     = base / P0;              // image        (block-uniform)
    const int a     = base - s * P0;
    const int i_idx = a / n_mm;               // ML row       (block-uniform)
    const int j0    = a - i_idx * n_mm;       // 4096-aligned within the row
    const int pi    = ml_idx[i_idx];

    if (sec == 0 || sec == 3) {               // value = pi (splat)
        const float fI = (float)pi;
        const f4 v = {fI, fI, fI, fI};
#pragma unroll
        for (int w = 0; w < 4; ++w) *(f4*)(dst + (w << 10)) = v;
        return;
    }

    if (sec == 1 || sec == 2) {               // value = pj
#pragma unroll
        for (int w = 0; w < 4; ++w) {
            int4 pj4 = *(const int4*)(mm_idx + j0 + (w << 10) + (tid << 2));
            f4 v = {(float)pj4.x, (float)pj4.y, (float)pj4.z, (float)pj4.w};
            *(f4*)(dst + (w << 10)) = v;
        }
        return;
    }

    // ---- sec 10..15: d2 / masks ----
    float svx, svy, svz;
    shift_vec_for(s, shifts, cell, svx, svy, svz);
    const float xi = pos[3 * pi + 0];
    const float yi = pos[3 * pi + 1];
    const float zi = pos[3 * pi + 2];
    const bool is_mask = (sec >= 12);
    float cut = 0.0f;
    if (is_mask) {
        float c = (sec >= 14) ? cutoffs[1] : cutoffs[0];
        cut = __fmul_rn(c, c);
    }
#pragma unroll
    for (int w = 0; w < 4; ++w) {
        int4 pj4 = *(const int4*)(mm_idx + j0 + (w << 10) + (tid << 2));
        int pjs[4] = {pj4.x, pj4.y, pj4.z, pj4.w};
        f4 v;
#pragma unroll
        for (int k = 0; k < 4; ++k) {
            int pj = pjs[k];
            float xj = pos[3 * pj + 0], yj = pos[3 * pj + 1], zj = pos[3 * pj + 2];
            // Rij = (pos_i - pos_j) + shift_vec, fp32 ops in reference order
            float dx = __fadd_rn(__fsub_rn(xi, xj), svx);
            float dy = __fadd_rn(__fsub_rn(yi, yj), svy);
            float dz = __fadd_rn(__fsub_rn(zi, zj), svz);
            float d2 = __fadd_rn(__fadd_rn(__fmul_rn(dx, dx), __fmul_rn(dy, dy)), __fmul_rn(dz, dz));
            v[k] = is_mask ? ((d2 < cut) ? 1.0f : 0.0f) : d2;
        }
        *(f4*)(dst + (w << 10)) = v;
    }
}

// ---------------------------------------------------------------------------
// Fallback: previous verified kernel (4 pairs/thread, 16 streams per wave).
// Used only when the 4096-alignment preconditions of nl_sections fail.
// ---------------------------------------------------------------------------
__global__ __launch_bounds__(256) void nl_kernel(
    const float* __restrict__ pos,
    const float* __restrict__ cell,
    const float* __restrict__ cutoffs,
    const int*   __restrict__ shifts,
    const int*   __restrict__ ml_idx,
    const int*   __restrict__ mm_idx,
    float* __restrict__ out,
    int n_mm, int P0, int P)
{
    int tid = blockIdx.x * blockDim.x + threadIdx.x;
    int p = tid << 2;
    if (p >= P) return;

    int s     = p / P0;
    int a     = p - s * P0;
    int i_idx = a / n_mm;
    int j0    = a - i_idx * n_mm;

    int pi = ml_idx[i_idx];
    float xi = pos[3 * pi + 0], yi = pos[3 * pi + 1], zi = pos[3 * pi + 2];

    float svx, svy, svz;
    shift_vec_for(s, shifts, cell, svx, svy, svz);

    float c0 = __fmul_rn(cutoffs[0], cutoffs[0]);
    float c1 = __fmul_rn(cutoffs[1], cutoffs[1]);

    float fI = (float)pi;
    f4 vI = {fI, fI, fI, fI};
    f4 vJ, vD, vM0, vM1;

    int4 pj4 = *(const int4*)(mm_idx + j0);
    int pjs[4] = {pj4.x, pj4.y, pj4.z, pj4.w};
#pragma unroll
    for (int k = 0; k < 4; ++k) {
        int pj = pjs[k];
        float xj = pos[3 * pj + 0], yj = pos[3 * pj + 1], zj = pos[3 * pj + 2];
        float dx = __fadd_rn(__fsub_rn(xi, xj), svx);
        float dy = __fadd_rn(__fsub_rn(yi, yj), svy);
        float dz = __fadd_rn(__fsub_rn(zi, zj), svz);
        float d2 = __fadd_rn(__fadd_rn(__fmul_rn(dx, dx), __fmul_rn(dy, dy)), __fmul_rn(dz, dz));
        vJ[k]  = (float)pj;
        vD[k]  = d2;
        vM0[k] = (d2 < c0) ? 1.0f : 0.0f;
        vM1[k] = (d2 < c1) ? 1.0f : 0.0f;
    }

    size_t Pz = (size_t)P;
    size_t pp = (size_t)p;
    *(f4*)(out + 0 * Pz + pp)  = vI;
    *(f4*)(out + 1 * Pz + pp)  = vJ;
    *(f4*)(out + 2 * Pz + pp)  = vJ;
    *(f4*)(out + 3 * Pz + pp)  = vI;
    *(f4*)(out + 10 * Pz + pp) = vD;
    *(f4*)(out + 11 * Pz + pp) = vD;
    *(f4*)(out + 12 * Pz + pp) = vM0;
    *(f4*)(out + 13 * Pz + pp) = vM0;
    *(f4*)(out + 14 * Pz + pp) = vM1;
    *(f4*)(out + 15 * Pz + pp) = vM1;

    int lane = (int)(threadIdx.x & 63);
    size_t pw = pp - (size_t)(lane << 2);
    float nx = -svx, ny = -svy, nz = -svz;
    float* nb = out + 4 * Pz + 3 * pw;
    float* qb = out + 7 * Pz + 3 * pw;

    if (pw + 256 <= (size_t)P) {
#pragma unroll
        for (int c = 0; c < 3; ++c) {
            int t = (lane + c) % 3;
            *(f4*)(nb + c * 256 + 4 * lane) = rot3(nx, ny, nz, t);
            *(f4*)(qb + c * 256 + 4 * lane) = rot3(svx, svy, svz, t);
        }
    } else {
        float* n0 = out + 4 * Pz + 3 * pp;
        float* q0 = out + 7 * Pz + 3 * pp;
#pragma unroll
        for (int r = 0; r < 4; ++r) {
            n0[3*r+0] = nx;  n0[3*r+1] = ny;  n0[3*r+2] = nz;
            q0[3*r+0] = svx; q0[3*r+1] = svy; q0[3*r+2] = svz;
        }
    }
}

extern "C" void kernel_launch(void* const* d_in, const int* in_sizes, int n_in,
                              void* d_out, int out_size, void* d_ws, size_t ws_size,
                              hipStream_t stream) {
    const float* pos    = (const float*)d_in[0];
    const float* cell   = (const float*)d_in[1];
    const float* cut    = (const float*)d_in[2];
    const int*   shifts = (const int*)d_in[3];
    const int*   ml     = (const int*)d_in[4];
    const int*   mm     = (const int*)d_in[5];

    int n_ml = in_sizes[4];
    int n_mm = in_sizes[5];
    int S    = in_sizes[3] / 3;
    int P0   = n_ml * n_mm;          // 128*8192 = 1048576
    int P    = (S + 1) * P0;         // 14*P0 = 14,680,064 ; out_size == 16*P

    // Fast path preconditions: one row / one image / one sign-half per
    // 4096-float block chunk, and all int32 index math in range.
    bool fast = (n_mm % 4096 == 0) && (P0 % 4096 == 0) && (P % 4096 == 0)
                && (P <= 0x7fffffff / 6);

    if (fast) {
        dim3 grid(P >> 12, 16);
        nl_sections<<<grid, 256, 0, stream>>>(pos, cell, cut, shifts, ml, mm,
                                              (float*)d_out, n_mm, P0, P);
    } else {
        int threads = (P + 3) / 4;
        int grid = (threads + 255) / 256;
        nl_kernel<<<grid, 256, 0, stream>>>(pos, cell, cut, shifts, ml, mm,
                                            (float*)d_out, n_mm, P0, P);
    }
}

// Round 2
// 908.705 us; speedup vs baseline: 1.0086x; 1.0086x over previous
//
#include <hip/hip_runtime.h>
#include <stdint.h>

typedef float f4 __attribute__((ext_vector_type(4)));

// Nontemporal (streaming, no-allocate) 16B store: global_store_dwordx4 ... nt.
// Theory: cached stores were incurring ~1x read amplification at the L2/MALL
// boundary (line allocation on write miss into a just-poisoned, dirty region),
// capping effective write BW at ~3.1 TB/s vs the fill's 6.2 TB/s.
__device__ __forceinline__ void st_nt(float* p, f4 v) {
    __builtin_nontemporal_store(v, (f4*)p);
}

// phase-rotated (x,y,z) repeating pattern: t=0 -> {x,y,z,x}, t=1 -> {y,z,x,y},
// t=2 -> {z,x,y,z}.
__device__ __forceinline__ f4 rot3(float x, float y, float z, int t) {
    float a0 = (t == 0) ? x : ((t == 1) ? y : z);
    float a1 = (t == 0) ? y : ((t == 1) ? z : x);
    float a2 = (t == 0) ? z : ((t == 1) ? x : y);
    f4 r = {a0, a1, a2, a0};
    return r;
}

// shift_vec = shift_frac @ cell, numpy accumulation order, no fma (bit-exact
// with the reference; image 0 is the zero shift).
__device__ __forceinline__ void shift_vec_for(
    int s, const int* __restrict__ shifts, const float* __restrict__ cell,
    float& svx, float& svy, float& svz)
{
    int sx = 0, sy = 0, sz = 0;
    if (s > 0) {
        sx = shifts[3 * (s - 1) + 0];
        sy = shifts[3 * (s - 1) + 1];
        sz = shifts[3 * (s - 1) + 2];
    }
    float fx = (float)sx, fy = (float)sy, fz = (float)sz;
    svx = __fadd_rn(__fadd_rn(__fmul_rn(fx, cell[0]), __fmul_rn(fy, cell[3])), __fmul_rn(fz, cell[6]));
    svy = __fadd_rn(__fadd_rn(__fmul_rn(fx, cell[1]), __fmul_rn(fy, cell[4])), __fmul_rn(fz, cell[7]));
    svz = __fadd_rn(__fadd_rn(__fmul_rn(fx, cell[2]), __fmul_rn(fy, cell[5])), __fmul_rn(fz, cell[8]));
}

// ---------------------------------------------------------------------------
// Sectioned kernel: one write stream per block, fill-like linear stores.
//
// Output layout (floats): [idx_i 2P][idx_j 2P][offsets 6P][d2 2P][masks 4P]
// viewed as 16 sections of P floats each:
//   0: idx_i lo (pi)   1: idx_i hi (pj)   2: idx_j lo (pj)   3: idx_j hi (pi)
//   4..9: offsets (6P stream: 3P of -shift rows, then 3P of +shift rows)
//   10,11: d2          12,13: mask c0     14,15: mask c1
//
// grid = (P/4096, 16); each block writes ONE contiguous 16 KB chunk of ONE
// section. Requires n_mm % 4096 == 0 (=> P0, P, 3*P0, 3P all 4096-aligned,
// so sec / sign-half / image / ML-row are all block-uniform).
// ---------------------------------------------------------------------------
__global__ __launch_bounds__(256) void nl_sections(
    const float* __restrict__ pos,      // (n_ml+n_mm, 3)
    const float* __restrict__ cell,     // (3,3) row-major
    const float* __restrict__ cutoffs,  // (2,)
    const int*   __restrict__ shifts,   // (S,3)
    const int*   __restrict__ ml_idx,   // (n_ml,)
    const int*   __restrict__ mm_idx,   // (n_mm,)
    float* __restrict__ out,            // float32, 16P elements
    int n_mm, int P0, int P)
{
    const int sec  = blockIdx.y;              // 0..15
    const int tid  = threadIdx.x;
    const int base = blockIdx.x << 12;        // first float of block's chunk
    float* __restrict__ dst =
        out + (size_t)sec * (size_t)P + (size_t)base + ((size_t)tid << 2);

    if (sec >= 4 && sec <= 9) {
        // ---- offsets: pure pattern write, (col = float_pos % 3) ----
        const int o0     = (sec - 4) * P + base;      // [0, 6P)
        const int threeP = 3 * P;
        const bool neg   = (o0 < threeP);             // block-uniform
        const int  oo    = neg ? o0 : (o0 - threeP);  // [0, 3P)
        const int  s     = oo / (3 * P0);             // image (block-uniform)
        float svx, svy, svz;
        shift_vec_for(s, shifts, cell, svx, svy, svz);
        if (neg) { svx = -svx; svy = -svy; svz = -svz; }   // exact
        const int t0 = (oo + (tid << 2)) % 3;
#pragma unroll
        for (int w = 0; w < 4; ++w) {
            int t = t0 + w;                    // 1024 % 3 == 1
            if (t >= 3) t -= 3;
            if (t >= 3) t -= 3;
            st_nt(dst + (w << 10), rot3(svx, svy, svz, t));
        }
        return;
    }

    // ---- pair-indexed sections: pair p = base + w*1024 + tid*4 + k ----
    const int s     = base / P0;              // image        (block-uniform)
    const int a     = base - s * P0;
    const int i_idx = a / n_mm;               // ML row       (block-uniform)
    const int j0    = a - i_idx * n_mm;       // 4096-aligned within the row
    const int pi    = ml_idx[i_idx];

    if (sec == 0 || sec == 3) {               // value = pi (splat)
        const float fI = (float)pi;
        const f4 v = {fI, fI, fI, fI};
#pragma unroll
        for (int w = 0; w < 4; ++w) st_nt(dst + (w << 10), v);
        return;
    }

    if (sec == 1 || sec == 2) {               // value = pj
#pragma unroll
        for (int w = 0; w < 4; ++w) {
            int4 pj4 = *(const int4*)(mm_idx + j0 + (w << 10) + (tid << 2));
            f4 v = {(float)pj4.x, (float)pj4.y, (float)pj4.z, (float)pj4.w};
            st_nt(dst + (w << 10), v);
        }
        return;
    }

    // ---- sec 10..15: d2 / masks ----
    float svx, svy, svz;
    shift_vec_for(s, shifts, cell, svx, svy, svz);
    const float xi = pos[3 * pi + 0];
    const float yi = pos[3 * pi + 1];
    const float zi = pos[3 * pi + 2];
    const bool is_mask = (sec >= 12);
    float cut = 0.0f;
    if (is_mask) {
        float c = (sec >= 14) ? cutoffs[1] : cutoffs[0];
        cut = __fmul_rn(c, c);
    }
#pragma unroll
    for (int w = 0; w < 4; ++w) {
        int4 pj4 = *(const int4*)(mm_idx + j0 + (w << 10) + (tid << 2));
        int pjs[4] = {pj4.x, pj4.y, pj4.z, pj4.w};
        f4 v;
#pragma unroll
        for (int k = 0; k < 4; ++k) {
            int pj = pjs[k];
            float xj = pos[3 * pj + 0], yj = pos[3 * pj + 1], zj = pos[3 * pj + 2];
            // Rij = (pos_i - pos_j) + shift_vec, fp32 ops in reference order
            float dx = __fadd_rn(__fsub_rn(xi, xj), svx);
            float dy = __fadd_rn(__fsub_rn(yi, yj), svy);
            float dz = __fadd_rn(__fsub_rn(zi, zj), svz);
            float d2 = __fadd_rn(__fadd_rn(__fmul_rn(dx, dx), __fmul_rn(dy, dy)), __fmul_rn(dz, dz));
            v[k] = is_mask ? ((d2 < cut) ? 1.0f : 0.0f) : d2;
        }
        st_nt(dst + (w << 10), v);
    }
}

// ---------------------------------------------------------------------------
// Fallback: 4 pairs/thread, 16 streams per wave (used only when the
// 4096-alignment preconditions of nl_sections fail). Also nontemporal.
// ---------------------------------------------------------------------------
__global__ __launch_bounds__(256) void nl_kernel(
    const float* __restrict__ pos,
    const float* __restrict__ cell,
    const float* __restrict__ cutoffs,
    const int*   __restrict__ shifts,
    const int*   __restrict__ ml_idx,
    const int*   __restrict__ mm_idx,
    float* __restrict__ out,
    int n_mm, int P0, int P)
{
    int tid = blockIdx.x * blockDim.x + threadIdx.x;
    int p = tid << 2;
    if (p >= P) return;

    int s     = p / P0;
    int a     = p - s * P0;
    int i_idx = a / n_mm;
    int j0    = a - i_idx * n_mm;

    int pi = ml_idx[i_idx];
    float xi = pos[3 * pi + 0], yi = pos[3 * pi + 1], zi = pos[3 * pi + 2];

    float svx, svy, svz;
    shift_vec_for(s, shifts, cell, svx, svy, svz);

    float c0 = __fmul_rn(cutoffs[0], cutoffs[0]);
    float c1 = __fmul_rn(cutoffs[1], cutoffs[1]);

    float fI = (float)pi;
    f4 vI = {fI, fI, fI, fI};
    f4 vJ, vD, vM0, vM1;

    int4 pj4 = *(const int4*)(mm_idx + j0);
    int pjs[4] = {pj4.x, pj4.y, pj4.z, pj4.w};
#pragma unroll
    for (int k = 0; k < 4; ++k) {
        int pj = pjs[k];
        float xj = pos[3 * pj + 0], yj = pos[3 * pj + 1], zj = pos[3 * pj + 2];
        float dx = __fadd_rn(__fsub_rn(xi, xj), svx);
        float dy = __fadd_rn(__fsub_rn(yi, yj), svy);
        float dz = __fadd_rn(__fsub_rn(zi, zj), svz);
        float d2 = __fadd_rn(__fadd_rn(__fmul_rn(dx, dx), __fmul_rn(dy, dy)), __fmul_rn(dz, dz));
        vJ[k]  = (float)pj;
        vD[k]  = d2;
        vM0[k] = (d2 < c0) ? 1.0f : 0.0f;
        vM1[k] = (d2 < c1) ? 1.0f : 0.0f;
    }

    size_t Pz = (size_t)P;
    size_t pp = (size_t)p;
    st_nt(out + 0 * Pz + pp,  vI);
    st_nt(out + 1 * Pz + pp,  vJ);
    st_nt(out + 2 * Pz + pp,  vJ);
    st_nt(out + 3 * Pz + pp,  vI);
    st_nt(out + 10 * Pz + pp, vD);
    st_nt(out + 11 * Pz + pp, vD);
    st_nt(out + 12 * Pz + pp, vM0);
    st_nt(out + 13 * Pz + pp, vM0);
    st_nt(out + 14 * Pz + pp, vM1);
    st_nt(out + 15 * Pz + pp, vM1);

    int lane = (int)(threadIdx.x & 63);
    size_t pw = pp - (size_t)(lane << 2);
    float nx = -svx, ny = -svy, nz = -svz;
    float* nb = out + 4 * Pz + 3 * pw;
    float* qb = out + 7 * Pz + 3 * pw;

    if (pw + 256 <= (size_t)P) {
#pragma unroll
        for (int c = 0; c < 3; ++c) {
            int t = (lane + c) % 3;
            st_nt(nb + c * 256 + 4 * lane, rot3(nx, ny, nz, t));
            st_nt(qb + c * 256 + 4 * lane, rot3(svx, svy, svz, t));
        }
    } else {
        float* n0 = out + 4 * Pz + 3 * pp;
        float* q0 = out + 7 * Pz + 3 * pp;
#pragma unroll
        for (int r = 0; r < 4; ++r) {
            n0[3*r+0] = nx;  n0[3*r+1] = ny;  n0[3*r+2] = nz;
            q0[3*r+0] = svx; q0[3*r+1] = svy; q0[3*r+2] = svz;
        }
    }
}

extern "C" void kernel_launch(void* const* d_in, const int* in_sizes, int n_in,
                              void* d_out, int out_size, void* d_ws, size_t ws_size,
                              hipStream_t stream) {
    const float* pos    = (const float*)d_in[0];
    const float* cell   = (const float*)d_in[1];
    const float* cut    = (const float*)d_in[2];
    const int*   shifts = (const int*)d_in[3];
    const int*   ml     = (const int*)d_in[4];
    const int*   mm     = (const int*)d_in[5];

    int n_ml = in_sizes[4];
    int n_mm = in_sizes[5];
    int S    = in_sizes[3] / 3;
    int P0   = n_ml * n_mm;          // 128*8192 = 1048576
    int P    = (S + 1) * P0;         // 14*P0 = 14,680,064 ; out_size == 16*P

    // Fast path preconditions: one row / one image / one sign-half per
    // 4096-float block chunk, and all int32 index math in range.
    bool fast = (n_mm % 4096 == 0) && (P0 % 4096 == 0) && (P % 4096 == 0)
                && (P <= 0x7fffffff / 6);

    if (fast) {
        dim3 grid(P >> 12, 16);
        nl_sections<<<grid, 256, 0, stream>>>(pos, cell, cut, shifts, ml, mm,
                                              (float*)d_out, n_mm, P0, P);
    } else {
        int threads = (P + 3) / 4;
        int grid = (threads + 255) / 256;
        nl_kernel<<<grid, 256, 0, stream>>>(pos, cell, cut, shifts, ml, mm,
                                            (float*)d_out, n_mm, P0, P);
    }
}